// Round 13
// baseline (165.266 us; speedup 1.0000x reference)
//
#include <hip/hip_runtime.h>

// SmearImages — round 12/13: r9 structure + camera-fastest grid (XCD pinning) + VGPR headroom.
// History: r6 lane~z 84us (TA-crack-bound); r8 lane=ix direct stores 101us (partial-sector
// write amp, 245MB); r11 lane=ix + LDS-transpose stores 48us, WRITE 65.5MB clean, but
// FETCH 71MB (~2x ideal): camera in blockIdx.y -> consecutive linear ids = same camera
// across all 8 XCDs -> every XCD L2 touches all 8 images (29.5MB >> 4MB L2).
// r12: grid=(8,128), bip=blockIdx.x -> linear id = bip + 8*row -> round-robin dispatch
// pins camera c to XCD c; its 3.7MB image fits the 4MB L2. Plus __launch_bounds__(256,4)
// (VGPR cap 128) to deepen the independent-gather pipeline (was 84 VGPR).
#define Bc   2
#define IPc  4
#define Cc   3
#define Hc   480
#define Wc   640
#define Nc   (64 * 64 * 64)
#define CHo  8
#define LDSP 36   // [64][36] floats: rows 144B (16B-aligned)

typedef float f32x4 __attribute__((ext_vector_type(4)));

// stage one channel: regs -> LDS tile [ix][iz_local] -> transposed NT store
#define STAGE(CH, ARR)                                                                 \
  do {                                                                                 \
    f32x4 w0 = { (ARR)[0], (ARR)[1], (ARR)[2], (ARR)[3] };                             \
    f32x4 w1 = { (ARR)[4], (ARR)[5], (ARR)[6], (ARR)[7] };                             \
    *reinterpret_cast<f32x4*>(&lds[ix * LDSP + wv * 8])     = w0;                      \
    *reinterpret_cast<f32x4*>(&lds[ix * LDSP + wv * 8 + 4]) = w1;                      \
    __syncthreads();                                                                   \
    float* __restrict__ op = out + ((size_t)(bip * CHo + (CH))) * Nc + iy * 64 + izc * 32; \
    _Pragma("unroll")                                                                  \
    for (int s = 0; s < 8; ++s) {                                                      \
      const int ixs = wv * 16 + s * 2 + (ix >> 5);                                     \
      const int izs = ix & 31;                                                         \
      __builtin_nontemporal_store(lds[ixs * LDSP + izs], op + ixs * 4096 + izs);       \
    }                                                                                  \
    __syncthreads();                                                                   \
  } while (0)

__global__ __launch_bounds__(256, 4) void smear_images_kernel(
    const float* __restrict__ images,
    const float* __restrict__ trans,
    const float* __restrict__ tcw,
    const float* __restrict__ coords,
    float* __restrict__ out)
{
    __shared__ float lds[64 * LDSP];

    const int t   = threadIdx.x;
    const int ix  = t & 63;          // lane = ix (outermost voxel axis)
    const int wv  = t >> 6;          // wave 0..3 -> iz sub-chunk
    const int bip = blockIdx.x;      // camera FASTEST -> pins camera to XCD
    const int gx  = blockIdx.y;      // 0..127
    const int iy  = gx >> 1;
    const int izc = gx & 1;          // 32-iz half
    const int b   = bip >> 2;

    // ---- per-camera parameters (wave-uniform -> scalar loads) ----
    const float* __restrict__ M = trans + bip * 12;
    const float m00 = M[0],  m01 = M[1],  m02 = M[2],  m03 = M[3];
    const float m10 = M[4],  m11 = M[5],  m12 = M[6],  m13 = M[7];
    const float m20 = M[8],  m21 = M[9],  m22 = M[10], m23 = M[11];

    const float* __restrict__ T = tcw + bip * 16;
    const float r00 = T[0], r01 = T[1], r02 = T[2],  t0 = T[3];
    const float r10 = T[4], r11 = T[5], r12 = T[6],  t1 = T[7];
    const float r20 = T[8], r21 = T[9], r22 = T[10], t2 = T[11];
    const float ccx = -(r00 * t0 + r10 * t1 + r20 * t2);
    const float ccy = -(r01 * t0 + r11 * t1 + r21 * t2);
    const float ccz = -(r02 * t0 + r12 * t1 + r22 * t2);

    const size_t img_base = (size_t)bip * Cc * Hc * Wc;
    const size_t cb       = (size_t)b * 3 * Nc;
    const int    n0       = ix * 4096 + iy * 64 + izc * 32 + wv * 8;  // 8 consecutive n

    // ---- coords (meshgrid): px=f(ix), py=f(iy), pz = 8 contiguous floats ----
    const float px = coords[cb + n0];
    const float py = coords[cb + (size_t)Nc + n0];
    const f32x4 pza = *reinterpret_cast<const f32x4*>(coords + cb + 2 * (size_t)Nc + n0);
    const f32x4 pzb = *reinterpret_cast<const f32x4*>(coords + cb + 2 * (size_t)Nc + n0 + 4);

    const float h0xy = m00 * px + m01 * py + m03;
    const float h1xy = m10 * px + m11 * py + m13;
    const float h2xy = m20 * px + m21 * py + m23;
    const float dxc  = px - ccx;
    const float dyc  = py - ccy;

    float rgb0[8], rgb1[8], rgb2[8], dep[8], vld[8], inv_[8], tmp[8];

    #pragma unroll
    for (int j = 0; j < 8; ++j) {
        const float pz = (j < 4) ? pza[j] : pzb[j - 4];

        const float h0 = h0xy + m02 * pz;
        const float h1 = h1xy + m12 * pz;
        const float h2 = h2xy + m22 * pz;

        const float depth = h2;
        const float safe  = (fabsf(depth) > 1e-8f) ? depth : 1e-8f;
        const float u = h0 / safe;
        const float v = h1 / safe;

        const float valid = (depth > 0.0f && u >= 0.0f && u <= (float)(Wc - 1) &&
                             v >= 0.0f && v <= (float)(Hc - 1)) ? 1.0f : 0.0f;

        const float x0f = floorf(u);
        const float y0f = floorf(v);
        const float wx  = u - x0f;
        const float wy  = v - y0f;
        const int   x0  = (int)x0f;
        const int   y0  = (int)y0f;
        const int   x1  = x0 + 1;
        const int   y1  = y0 + 1;

        const float w00 = (1.0f - wx) * (1.0f - wy);
        const float w10 = wx * (1.0f - wy);
        const float w01 = (1.0f - wx) * wy;
        const float w11 = wx * wy;

        const bool ibx0 = (x0 >= 0) & (x0 < Wc);
        const bool ibx1 = (x1 >= 0) & (x1 < Wc);
        const bool iby0 = (y0 >= 0) & (y0 < Hc);
        const bool iby1 = (y1 >= 0) & (y1 < Hc);

        const int cx0 = min(max(x0, 0), Wc - 1);
        const int cx1 = min(max(x1, 0), Wc - 1);
        const int cy0 = min(max(y0, 0), Hc - 1);
        const int cy1 = min(max(y1, 0), Hc - 1);

        const int row0 = cy0 * Wc;
        const int row1 = cy1 * Wc;

        {
            const float* __restrict__ img = images + img_base;
            const float v00 = (ibx0 & iby0) ? img[row0 + cx0] : 0.0f;
            const float v10 = (ibx1 & iby0) ? img[row0 + cx1] : 0.0f;
            const float v01 = (ibx0 & iby1) ? img[row1 + cx0] : 0.0f;
            const float v11 = (ibx1 & iby1) ? img[row1 + cx1] : 0.0f;
            rgb0[j] = v00 * w00 + v10 * w10 + v01 * w01 + v11 * w11;
        }
        {
            const float* __restrict__ img = images + img_base + (size_t)(Hc * Wc);
            const float v00 = (ibx0 & iby0) ? img[row0 + cx0] : 0.0f;
            const float v10 = (ibx1 & iby0) ? img[row0 + cx1] : 0.0f;
            const float v01 = (ibx0 & iby1) ? img[row1 + cx0] : 0.0f;
            const float v11 = (ibx1 & iby1) ? img[row1 + cx1] : 0.0f;
            rgb1[j] = v00 * w00 + v10 * w10 + v01 * w01 + v11 * w11;
        }
        {
            const float* __restrict__ img = images + img_base + 2 * (size_t)(Hc * Wc);
            const float v00 = (ibx0 & iby0) ? img[row0 + cx0] : 0.0f;
            const float v10 = (ibx1 & iby0) ? img[row0 + cx1] : 0.0f;
            const float v01 = (ibx0 & iby1) ? img[row1 + cx0] : 0.0f;
            const float v11 = (ibx1 & iby1) ? img[row1 + cx1] : 0.0f;
            rgb2[j] = v00 * w00 + v10 * w10 + v01 * w01 + v11 * w11;
        }

        dep[j] = depth;
        vld[j] = valid;

        const float dz = pz - ccz;
        const float nrm = sqrtf(dxc * dxc + dyc * dyc + dz * dz);
        inv_[j] = 1.0f / fmaxf(nrm, 1e-8f);
    }

    STAGE(0, rgb0);
    STAGE(1, rgb1);
    STAGE(2, rgb2);
    STAGE(3, dep);
    STAGE(4, vld);

    #pragma unroll
    for (int j = 0; j < 8; ++j) tmp[j] = dxc * inv_[j];
    STAGE(5, tmp);
    #pragma unroll
    for (int j = 0; j < 8; ++j) tmp[j] = dyc * inv_[j];
    STAGE(6, tmp);
    #pragma unroll
    for (int j = 0; j < 8; ++j) {
        const float pz = (j < 4) ? pza[j] : pzb[j - 4];
        tmp[j] = (pz - ccz) * inv_[j];
    }
    STAGE(7, tmp);
}

extern "C" void kernel_launch(void* const* d_in, const int* in_sizes, int n_in,
                              void* d_out, int out_size, void* d_ws, size_t ws_size,
                              hipStream_t stream) {
    const float* images = (const float*)d_in[0];
    const float* trans  = (const float*)d_in[1];
    const float* tcw    = (const float*)d_in[2];
    const float* coords = (const float*)d_in[3];
    float* out = (float*)d_out;

    dim3 grid(Bc * IPc, 128);   // camera fastest: linear id = bip + 8*row -> XCD = bip
    dim3 block(256);
    smear_images_kernel<<<grid, block, 0, stream>>>(images, trans, tcw, coords, out);
}

// Round 14
// 128.470 us; speedup vs baseline: 1.2864x; 1.2864x over previous
//
#include <hip/hip_runtime.h>

// SmearImages — round 14: r11 codegen (plain launch_bounds, 84 VGPR, no spills)
// + camera-fastest grid ONLY (isolating the XCD-pinning change).
// History: r6 lane~z 84us; r8 lane=ix direct stores 101us (write amp 245MB);
// r11 lane=ix + LDS-transpose stores 48us (WRITE 65.5MB clean, FETCH 71MB, latency-bound);
// r13 = r11 + camera-grid + launch_bounds(256,4): REGRESSED to 88us — the (,4) capped
// VGPR at 64 -> scratch spills -> +70MB jittery HBM writes, VALU 9.9%. FETCH 71->65
// suggests camera-pinning itself helps. r14 keeps the grid, drops the (,4).
#define Bc   2
#define IPc  4
#define Cc   3
#define Hc   480
#define Wc   640
#define Nc   (64 * 64 * 64)
#define CHo  8
#define LDSP 36   // [64][36] floats: rows 144B (16B-aligned)

typedef float f32x4 __attribute__((ext_vector_type(4)));

// stage one channel: regs -> LDS tile [ix][iz_local] -> transposed NT store
#define STAGE(CH, ARR)                                                                 \
  do {                                                                                 \
    f32x4 w0 = { (ARR)[0], (ARR)[1], (ARR)[2], (ARR)[3] };                             \
    f32x4 w1 = { (ARR)[4], (ARR)[5], (ARR)[6], (ARR)[7] };                             \
    *reinterpret_cast<f32x4*>(&lds[ix * LDSP + wv * 8])     = w0;                      \
    *reinterpret_cast<f32x4*>(&lds[ix * LDSP + wv * 8 + 4]) = w1;                      \
    __syncthreads();                                                                   \
    float* __restrict__ op = out + ((size_t)(bip * CHo + (CH))) * Nc + iy * 64 + izc * 32; \
    _Pragma("unroll")                                                                  \
    for (int s = 0; s < 8; ++s) {                                                      \
      const int ixs = wv * 16 + s * 2 + (ix >> 5);                                     \
      const int izs = ix & 31;                                                         \
      __builtin_nontemporal_store(lds[ixs * LDSP + izs], op + ixs * 4096 + izs);       \
    }                                                                                  \
    __syncthreads();                                                                   \
  } while (0)

__global__ __launch_bounds__(256) void smear_images_kernel(
    const float* __restrict__ images,
    const float* __restrict__ trans,
    const float* __restrict__ tcw,
    const float* __restrict__ coords,
    float* __restrict__ out)
{
    __shared__ float lds[64 * LDSP];

    const int t   = threadIdx.x;
    const int ix  = t & 63;          // lane = ix (outermost voxel axis)
    const int wv  = t >> 6;          // wave 0..3 -> iz sub-chunk
    const int bip = blockIdx.x;      // camera FASTEST -> linear id = bip + 8*gx -> XCD = bip
    const int gx  = blockIdx.y;      // 0..127
    const int iy  = gx >> 1;
    const int izc = gx & 1;          // 32-iz half
    const int b   = bip >> 2;

    // ---- per-camera parameters (wave-uniform -> scalar loads) ----
    const float* __restrict__ M = trans + bip * 12;
    const float m00 = M[0],  m01 = M[1],  m02 = M[2],  m03 = M[3];
    const float m10 = M[4],  m11 = M[5],  m12 = M[6],  m13 = M[7];
    const float m20 = M[8],  m21 = M[9],  m22 = M[10], m23 = M[11];

    const float* __restrict__ T = tcw + bip * 16;
    const float r00 = T[0], r01 = T[1], r02 = T[2],  t0 = T[3];
    const float r10 = T[4], r11 = T[5], r12 = T[6],  t1 = T[7];
    const float r20 = T[8], r21 = T[9], r22 = T[10], t2 = T[11];
    const float ccx = -(r00 * t0 + r10 * t1 + r20 * t2);
    const float ccy = -(r01 * t0 + r11 * t1 + r21 * t2);
    const float ccz = -(r02 * t0 + r12 * t1 + r22 * t2);

    const size_t img_base = (size_t)bip * Cc * Hc * Wc;
    const size_t cb       = (size_t)b * 3 * Nc;
    const int    n0       = ix * 4096 + iy * 64 + izc * 32 + wv * 8;  // 8 consecutive n

    // ---- coords (meshgrid): px=f(ix), py=f(iy), pz = 8 contiguous floats ----
    const float px = coords[cb + n0];
    const float py = coords[cb + (size_t)Nc + n0];
    const f32x4 pza = *reinterpret_cast<const f32x4*>(coords + cb + 2 * (size_t)Nc + n0);
    const f32x4 pzb = *reinterpret_cast<const f32x4*>(coords + cb + 2 * (size_t)Nc + n0 + 4);

    const float h0xy = m00 * px + m01 * py + m03;
    const float h1xy = m10 * px + m11 * py + m13;
    const float h2xy = m20 * px + m21 * py + m23;
    const float dxc  = px - ccx;
    const float dyc  = py - ccy;

    float rgb0[8], rgb1[8], rgb2[8], dep[8], vld[8], inv_[8], tmp[8];

    #pragma unroll
    for (int j = 0; j < 8; ++j) {
        const float pz = (j < 4) ? pza[j] : pzb[j - 4];

        const float h0 = h0xy + m02 * pz;
        const float h1 = h1xy + m12 * pz;
        const float h2 = h2xy + m22 * pz;

        const float depth = h2;
        const float safe  = (fabsf(depth) > 1e-8f) ? depth : 1e-8f;
        const float u = h0 / safe;
        const float v = h1 / safe;

        const float valid = (depth > 0.0f && u >= 0.0f && u <= (float)(Wc - 1) &&
                             v >= 0.0f && v <= (float)(Hc - 1)) ? 1.0f : 0.0f;

        const float x0f = floorf(u);
        const float y0f = floorf(v);
        const float wx  = u - x0f;
        const float wy  = v - y0f;
        const int   x0  = (int)x0f;
        const int   y0  = (int)y0f;
        const int   x1  = x0 + 1;
        const int   y1  = y0 + 1;

        const float w00 = (1.0f - wx) * (1.0f - wy);
        const float w10 = wx * (1.0f - wy);
        const float w01 = (1.0f - wx) * wy;
        const float w11 = wx * wy;

        const bool ibx0 = (x0 >= 0) & (x0 < Wc);
        const bool ibx1 = (x1 >= 0) & (x1 < Wc);
        const bool iby0 = (y0 >= 0) & (y0 < Hc);
        const bool iby1 = (y1 >= 0) & (y1 < Hc);

        const int cx0 = min(max(x0, 0), Wc - 1);
        const int cx1 = min(max(x1, 0), Wc - 1);
        const int cy0 = min(max(y0, 0), Hc - 1);
        const int cy1 = min(max(y1, 0), Hc - 1);

        const int row0 = cy0 * Wc;
        const int row1 = cy1 * Wc;

        {
            const float* __restrict__ img = images + img_base;
            const float v00 = (ibx0 & iby0) ? img[row0 + cx0] : 0.0f;
            const float v10 = (ibx1 & iby0) ? img[row0 + cx1] : 0.0f;
            const float v01 = (ibx0 & iby1) ? img[row1 + cx0] : 0.0f;
            const float v11 = (ibx1 & iby1) ? img[row1 + cx1] : 0.0f;
            rgb0[j] = v00 * w00 + v10 * w10 + v01 * w01 + v11 * w11;
        }
        {
            const float* __restrict__ img = images + img_base + (size_t)(Hc * Wc);
            const float v00 = (ibx0 & iby0) ? img[row0 + cx0] : 0.0f;
            const float v10 = (ibx1 & iby0) ? img[row0 + cx1] : 0.0f;
            const float v01 = (ibx0 & iby1) ? img[row1 + cx0] : 0.0f;
            const float v11 = (ibx1 & iby1) ? img[row1 + cx1] : 0.0f;
            rgb1[j] = v00 * w00 + v10 * w10 + v01 * w01 + v11 * w11;
        }
        {
            const float* __restrict__ img = images + img_base + 2 * (size_t)(Hc * Wc);
            const float v00 = (ibx0 & iby0) ? img[row0 + cx0] : 0.0f;
            const float v10 = (ibx1 & iby0) ? img[row0 + cx1] : 0.0f;
            const float v01 = (ibx0 & iby1) ? img[row1 + cx0] : 0.0f;
            const float v11 = (ibx1 & iby1) ? img[row1 + cx1] : 0.0f;
            rgb2[j] = v00 * w00 + v10 * w10 + v01 * w01 + v11 * w11;
        }

        dep[j] = depth;
        vld[j] = valid;

        const float dz = pz - ccz;
        const float nrm = sqrtf(dxc * dxc + dyc * dyc + dz * dz);
        inv_[j] = 1.0f / fmaxf(nrm, 1e-8f);
    }

    STAGE(0, rgb0);
    STAGE(1, rgb1);
    STAGE(2, rgb2);
    STAGE(3, dep);
    STAGE(4, vld);

    #pragma unroll
    for (int j = 0; j < 8; ++j) tmp[j] = dxc * inv_[j];
    STAGE(5, tmp);
    #pragma unroll
    for (int j = 0; j < 8; ++j) tmp[j] = dyc * inv_[j];
    STAGE(6, tmp);
    #pragma unroll
    for (int j = 0; j < 8; ++j) {
        const float pz = (j < 4) ? pza[j] : pzb[j - 4];
        tmp[j] = (pz - ccz) * inv_[j];
    }
    STAGE(7, tmp);
}

extern "C" void kernel_launch(void* const* d_in, const int* in_sizes, int n_in,
                              void* d_out, int out_size, void* d_ws, size_t ws_size,
                              hipStream_t stream) {
    const float* images = (const float*)d_in[0];
    const float* trans  = (const float*)d_in[1];
    const float* tcw    = (const float*)d_in[2];
    const float* coords = (const float*)d_in[3];
    float* out = (float*)d_out;

    dim3 grid(Bc * IPc, 128);   // camera fastest: linear id = bip + 8*gx -> XCD = bip
    dim3 block(256);
    smear_images_kernel<<<grid, block, 0, stream>>>(images, trans, tcw, coords, out);
}

// Round 16
// 122.595 us; speedup vs baseline: 1.3481x; 1.0479x over previous
//
#include <hip/hip_runtime.h>

// SmearImages — round 15/16: r14 + float2 corner-pair gathers (12 -> 6 VMEM/point).
// History: r6 lane~z 84us; r11 lane=ix + LDS-transpose stores 48us (FETCH 71MB);
// r13 +camera-grid+LB(256,4): 88us (VGPR capped 64 -> spills); r14 camera-grid only:
// 52us, FETCH 23.8MB (XCD-pinned: camera c -> XCD c L2), WRITE 65.5MB clean, but
// transaction-bound: per wave-gather u spans ~320px ~21 lines; x0/x1 gathers walk
// the same lines twice. r15 merges each (x0,x1) pair into one float2 gather:
// pair at xb=min(cx0,W-2), corners = pair[cx0-xb], pair[cx1-xb], then zero-mask.
#define Bc   2
#define IPc  4
#define Cc   3
#define Hc   480
#define Wc   640
#define Nc   (64 * 64 * 64)
#define CHo  8
#define LDSP 36   // [64][36] floats: rows 144B (16B-aligned)

typedef float f32x4 __attribute__((ext_vector_type(4)));
typedef float f32x2_a4 __attribute__((ext_vector_type(2), aligned(4)));  // 4B-aligned pair load

// stage one channel: regs -> LDS tile [ix][iz_local] -> transposed NT store
#define STAGE(CH, ARR)                                                                 \
  do {                                                                                 \
    f32x4 w0 = { (ARR)[0], (ARR)[1], (ARR)[2], (ARR)[3] };                             \
    f32x4 w1 = { (ARR)[4], (ARR)[5], (ARR)[6], (ARR)[7] };                             \
    *reinterpret_cast<f32x4*>(&lds[ix * LDSP + wv * 8])     = w0;                      \
    *reinterpret_cast<f32x4*>(&lds[ix * LDSP + wv * 8 + 4]) = w1;                      \
    __syncthreads();                                                                   \
    float* __restrict__ op = out + ((size_t)(bip * CHo + (CH))) * Nc + iy * 64 + izc * 32; \
    _Pragma("unroll")                                                                  \
    for (int s = 0; s < 8; ++s) {                                                      \
      const int ixs = wv * 16 + s * 2 + (ix >> 5);                                     \
      const int izs = ix & 31;                                                         \
      __builtin_nontemporal_store(lds[ixs * LDSP + izs], op + ixs * 4096 + izs);       \
    }                                                                                  \
    __syncthreads();                                                                   \
  } while (0)

__global__ __launch_bounds__(256) void smear_images_kernel(
    const float* __restrict__ images,
    const float* __restrict__ trans,
    const float* __restrict__ tcw,
    const float* __restrict__ coords,
    float* __restrict__ out)
{
    __shared__ float lds[64 * LDSP];

    const int t   = threadIdx.x;
    const int ix  = t & 63;          // lane = ix (outermost voxel axis)
    const int wv  = t >> 6;          // wave 0..3 -> iz sub-chunk
    const int bip = blockIdx.x;      // camera FASTEST -> linear id = bip + 8*gx -> XCD = bip
    const int gx  = blockIdx.y;      // 0..127
    const int iy  = gx >> 1;
    const int izc = gx & 1;          // 32-iz half
    const int b   = bip >> 2;

    // ---- per-camera parameters (wave-uniform -> scalar loads) ----
    const float* __restrict__ M = trans + bip * 12;
    const float m00 = M[0],  m01 = M[1],  m02 = M[2],  m03 = M[3];
    const float m10 = M[4],  m11 = M[5],  m12 = M[6],  m13 = M[7];
    const float m20 = M[8],  m21 = M[9],  m22 = M[10], m23 = M[11];

    const float* __restrict__ T = tcw + bip * 16;
    const float r00 = T[0], r01 = T[1], r02 = T[2],  t0 = T[3];
    const float r10 = T[4], r11 = T[5], r12 = T[6],  t1 = T[7];
    const float r20 = T[8], r21 = T[9], r22 = T[10], t2 = T[11];
    const float ccx = -(r00 * t0 + r10 * t1 + r20 * t2);
    const float ccy = -(r01 * t0 + r11 * t1 + r21 * t2);
    const float ccz = -(r02 * t0 + r12 * t1 + r22 * t2);

    const size_t img_base = (size_t)bip * Cc * Hc * Wc;
    const size_t cb       = (size_t)b * 3 * Nc;
    const int    n0       = ix * 4096 + iy * 64 + izc * 32 + wv * 8;  // 8 consecutive n

    // ---- coords (meshgrid): px=f(ix), py=f(iy), pz = 8 contiguous floats ----
    const float px = coords[cb + n0];
    const float py = coords[cb + (size_t)Nc + n0];
    const f32x4 pza = *reinterpret_cast<const f32x4*>(coords + cb + 2 * (size_t)Nc + n0);
    const f32x4 pzb = *reinterpret_cast<const f32x4*>(coords + cb + 2 * (size_t)Nc + n0 + 4);

    const float h0xy = m00 * px + m01 * py + m03;
    const float h1xy = m10 * px + m11 * py + m13;
    const float h2xy = m20 * px + m21 * py + m23;
    const float dxc  = px - ccx;
    const float dyc  = py - ccy;

    float rgb0[8], rgb1[8], rgb2[8], dep[8], vld[8], inv_[8], tmp[8];

    #pragma unroll
    for (int j = 0; j < 8; ++j) {
        const float pz = (j < 4) ? pza[j] : pzb[j - 4];

        const float h0 = h0xy + m02 * pz;
        const float h1 = h1xy + m12 * pz;
        const float h2 = h2xy + m22 * pz;

        const float depth = h2;
        const float safe  = (fabsf(depth) > 1e-8f) ? depth : 1e-8f;
        const float u = h0 / safe;
        const float v = h1 / safe;

        const float valid = (depth > 0.0f && u >= 0.0f && u <= (float)(Wc - 1) &&
                             v >= 0.0f && v <= (float)(Hc - 1)) ? 1.0f : 0.0f;

        const float x0f = floorf(u);
        const float y0f = floorf(v);
        const float wx  = u - x0f;
        const float wy  = v - y0f;
        const int   x0  = (int)x0f;
        const int   y0  = (int)y0f;
        const int   x1  = x0 + 1;
        const int   y1  = y0 + 1;

        const float w00 = (1.0f - wx) * (1.0f - wy);
        const float w10 = wx * (1.0f - wy);
        const float w01 = (1.0f - wx) * wy;
        const float w11 = wx * wy;

        const bool ibx0 = (x0 >= 0) & (x0 < Wc);
        const bool ibx1 = (x1 >= 0) & (x1 < Wc);
        const bool iby0 = (y0 >= 0) & (y0 < Hc);
        const bool iby1 = (y1 >= 0) & (y1 < Hc);

        const int cx0 = min(max(x0, 0), Wc - 1);
        const int cx1 = min(max(x1, 0), Wc - 1);
        const int cy0 = min(max(y0, 0), Hc - 1);
        const int cy1 = min(max(y1, 0), Hc - 1);

        // corner-pair base: pair[0]=img[xb], pair[1]=img[xb+1]; cx0,cx1 in {xb,xb+1}
        const int  xb   = min(cx0, Wc - 2);
        const bool s0   = (cx0 != xb);   // select for corner x0
        const bool s1   = (cx1 != xb);   // select for corner x1
        const int  row0 = cy0 * Wc + xb;
        const int  row1 = cy1 * Wc + xb;

        #pragma unroll
        for (int c = 0; c < Cc; ++c) {
            const float* __restrict__ img = images + img_base + (size_t)c * (Hc * Wc);
            const f32x2_a4 p0 = *reinterpret_cast<const f32x2_a4*>(img + row0);
            const f32x2_a4 p1 = *reinterpret_cast<const f32x2_a4*>(img + row1);
            const float v00 = (ibx0 & iby0) ? (s0 ? p0.y : p0.x) : 0.0f;
            const float v10 = (ibx1 & iby0) ? (s1 ? p0.y : p0.x) : 0.0f;
            const float v01 = (ibx0 & iby1) ? (s0 ? p1.y : p1.x) : 0.0f;
            const float v11 = (ibx1 & iby1) ? (s1 ? p1.y : p1.x) : 0.0f;
            const float sres = v00 * w00 + v10 * w10 + v01 * w01 + v11 * w11;
            if (c == 0) rgb0[j] = sres;
            else if (c == 1) rgb1[j] = sres;
            else rgb2[j] = sres;
        }

        dep[j] = depth;
        vld[j] = valid;

        const float dz = pz - ccz;
        const float nrm = sqrtf(dxc * dxc + dyc * dyc + dz * dz);
        inv_[j] = 1.0f / fmaxf(nrm, 1e-8f);
    }

    STAGE(0, rgb0);
    STAGE(1, rgb1);
    STAGE(2, rgb2);
    STAGE(3, dep);
    STAGE(4, vld);

    #pragma unroll
    for (int j = 0; j < 8; ++j) tmp[j] = dxc * inv_[j];
    STAGE(5, tmp);
    #pragma unroll
    for (int j = 0; j < 8; ++j) tmp[j] = dyc * inv_[j];
    STAGE(6, tmp);
    #pragma unroll
    for (int j = 0; j < 8; ++j) {
        const float pz = (j < 4) ? pza[j] : pzb[j - 4];
        tmp[j] = (pz - ccz) * inv_[j];
    }
    STAGE(7, tmp);
}

extern "C" void kernel_launch(void* const* d_in, const int* in_sizes, int n_in,
                              void* d_out, int out_size, void* d_ws, size_t ws_size,
                              hipStream_t stream) {
    const float* images = (const float*)d_in[0];
    const float* trans  = (const float*)d_in[1];
    const float* tcw    = (const float*)d_in[2];
    const float* coords = (const float*)d_in[3];
    float* out = (float*)d_out;

    dim3 grid(Bc * IPc, 128);   // camera fastest: linear id = bip + 8*gx -> XCD = bip
    dim3 block(256);
    smear_images_kernel<<<grid, block, 0, stream>>>(images, trans, tcw, coords, out);
}